// Round 1
// baseline (278.069 us; speedup 1.0000x reference)
//
#include <hip/hip_runtime.h>

#define FDIM   251
#define NFILT  80
#define WPAD   264        // filter row padded to 264 (33 * 8), zeros past 250
#define T_IN   64000
#define T_OUT  63750      // 64000 - 251 + 1
#define NTB    1024       // output time positions per block
#define XSTAGE 1312       // staged x floats per block (covers prefetch overreach)
#define XS_PAD 1640       // XSTAGE * 20/16 (4-float pad every 16)

// LDS address padding: +4 floats every 16 -> per-lane stride-16-element b128
// reads become stride-20-dword = bank-conflict-free.
__device__ __forceinline__ int padadr(int e) { return e + ((e >> 4) << 2); }

// ---------------------------------------------------------------------------
// Filter construction: one block per filter.
// ---------------------------------------------------------------------------
__device__ __forceinline__ void norm_pm1_shared(float* a, float* scratch, int tid) {
  float v  = (tid < FDIM) ? a[tid] : 0.f;
  float mn = (tid < FDIM) ? v : 1e30f;
  float mx = (tid < FDIM) ? v : -1e30f;
  #pragma unroll
  for (int o = 32; o > 0; o >>= 1) {
    mn = fminf(mn, __shfl_down(mn, o));
    mx = fmaxf(mx, __shfl_down(mx, o));
  }
  const int wid = tid >> 6;
  if ((tid & 63) == 0) { scratch[wid] = mn; scratch[4 + wid] = mx; }
  __syncthreads();
  if (tid == 0) {
    scratch[0] = fminf(fminf(scratch[0], scratch[1]), fminf(scratch[2], scratch[3]));
    scratch[4] = fmaxf(fmaxf(scratch[4], scratch[5]), fmaxf(scratch[6], scratch[7]));
  }
  __syncthreads();
  const float gmn = scratch[0], gmx = scratch[4];
  const float nv = 2.f * (v - gmn) / (gmx - gmn + 1e-6f) - 1.f;
  __syncthreads();                       // scratch reuse safe
  float s = (tid < FDIM) ? nv : 0.f;
  #pragma unroll
  for (int o = 32; o > 0; o >>= 1) s += __shfl_down(s, o);
  if ((tid & 63) == 0) scratch[wid] = s;
  __syncthreads();
  if (tid == 0) scratch[0] = (scratch[0] + scratch[1] + scratch[2] + scratch[3]) / 251.f;
  __syncthreads();
  const float mean = scratch[0];
  if (tid < FDIM) a[tid] = nv - mean;
  __syncthreads();
}

__global__ __launch_bounds__(256) void build_filters_kernel(
    const float* __restrict__ nf1, const float* __restrict__ nf2,
    const float* __restrict__ nf3, const float* __restrict__ nf4,
    const float* __restrict__ amp1, const float* __restrict__ amp2,
    float* __restrict__ Wf) {
  __shared__ float ir1[FDIM], ir2[FDIM], casc[FDIM];
  __shared__ float scratch[8];
  const int f = blockIdx.x, tid = threadIdx.x;
  const float FS  = 16000.f;
  const float MF  = 50.f / 16000.f;
  const float PIF = 3.14159265358979323846f;
  const float TPI = 6.28318530717958647692f;

  const float f1 = fminf(fmaxf(fabsf(nf1[f]) + MF, 0.f), 0.5f);
  const float f2 = fminf(fmaxf(f1 + fabsf(nf2[f] - f1) + MF, 0.f), 0.5f);
  const float f3 = fminf(fmaxf(fabsf(nf3[f]) + MF, 0.f), 0.5f);
  const float f4 = fminf(fmaxf(f3 + fabsf(nf4[f] - f3) + MF, 0.f), 0.5f);
  const float a1 = fabsf(amp1[f]);
  const float a2 = fabsf(amp2[f]);

  if (tid < FDIM) {
    const float t = (float)(tid + 1) / FS;
    {
      const float fcs = 0.5f * (f1 + f2) * FS, bws = (f2 - f1) * FS;
      const float pb = PIF * bws;
      ir1[tid] = a1 * expf(-2.f * pb * pb * (t * t)) * cosf(TPI * fcs * t);
    }
    {
      const float fcs = 0.5f * (f3 + f4) * FS, bws = (f4 - f3) * FS;
      const float pb = PIF * bws;
      ir2[tid] = a2 * expf(-2.f * pb * pb * (t * t)) * cosf(TPI * fcs * t);
    }
  }
  __syncthreads();
  norm_pm1_shared(ir1, scratch, tid);
  norm_pm1_shared(ir2, scratch, tid);

  // casc[i] = sum_p ir1[p] * ir2[p + 125 - i],  p + 125 - i in [0, 250]
  if (tid < FDIM) {
    const int i = tid;
    const int plo = (i - 125 > 0) ? (i - 125) : 0;
    const int phi = (i + 125 < 250) ? (i + 125) : 250;
    float s = 0.f;
    for (int p = plo; p <= phi; ++p) s += ir1[p] * ir2[p + 125 - i];
    casc[i] = s;
  }
  __syncthreads();
  norm_pm1_shared(casc, scratch, tid);

  for (int i = tid; i < WPAD; i += 256) {
    float v = 0.f;
    if (i < FDIM) {
      const float win = 0.54f - 0.46f * cosf(TPI * ((float)i / 250.f));
      v = casc[i] * win;
    }
    Wf[(size_t)f * WPAD + i] = v;
  }
}

// ---------------------------------------------------------------------------
// Convolution: block = 1 batch x 4 filters x 1024 time positions.
// Thread (tf = tid>>6, tt = tid&63) computes 16 consecutive outputs for one
// filter with a 24-float rolling register window (static rotation, unroll x3).
// ---------------------------------------------------------------------------
__device__ __forceinline__ float pick6(const float4& a, const float4& b,
                                       const float4& c, const float4& d,
                                       const float4& e, const float4& f, int q) {
  const float4& s = (q < 4) ? a : (q < 8) ? b : (q < 12) ? c
                   : (q < 16) ? d : (q < 20) ? e : f;
  return ((const float*)&s)[q & 3];
}

#define LD4(e) (*(const float4*)&xs[padadr(e)])

#define ITER(K0, S0, S1, S2, S3, S4, S5) do {                                   \
    const int k0_ = (K0);                                                       \
    const float4 w0 = *(const float4*)&wsrow[k0_];                              \
    const float4 w1 = *(const float4*)&wsrow[k0_ + 4];                          \
    _Pragma("unroll")                                                           \
    for (int kk = 0; kk < 8; ++kk) {                                            \
      const float wv = (kk < 4) ? ((const float*)&w0)[kk]                       \
                                : ((const float*)&w1)[kk - 4];                  \
      _Pragma("unroll")                                                         \
      for (int r = 0; r < 16; ++r)                                              \
        acc[r] = fmaf(wv, pick6(S0, S1, S2, S3, S4, S5, r + kk), acc[r]);       \
    }                                                                           \
    const int en_ = t0 + k0_ + 24;                                              \
    S0 = LD4(en_); S1 = LD4(en_ + 4);                                           \
  } while (0)

__global__ __launch_bounds__(256) void conv_kernel(
    const float* __restrict__ xin, const float* __restrict__ Wf,
    float* __restrict__ outp) {
  __shared__ float xs[XS_PAD];
  __shared__ float ws[4 * WPAD];
  const int tid = threadIdx.x;
  const int tc = blockIdx.x, fg = blockIdx.y, b = blockIdx.z;
  const int base = tc * NTB;

  for (int i = tid; i < XSTAGE; i += 256) {
    const int gi = base + i;
    xs[padadr(i)] = (gi < T_IN) ? xin[(size_t)b * T_IN + gi] : 0.f;
  }
  for (int i = tid; i < 4 * WPAD; i += 256) {
    ws[i] = Wf[(size_t)fg * 4 * WPAD + i];
  }
  __syncthreads();

  const int tf = tid >> 6, tt = tid & 63;
  const int t0 = tt * 16;
  const float* wsrow = &ws[tf * WPAD];

  float acc[16];
  #pragma unroll
  for (int r = 0; r < 16; ++r) acc[r] = 0.f;

  float4 A0 = LD4(t0),      A1 = LD4(t0 + 4);
  float4 B0 = LD4(t0 + 8),  B1 = LD4(t0 + 12);
  float4 C0 = LD4(t0 + 16), C1 = LD4(t0 + 20);

  for (int jt = 0; jt < 11; ++jt) {       // 33 k-steps of 8 -> k = 0..263 (zero-padded past 250)
    const int k0 = 24 * jt;
    ITER(k0,      A0, A1, B0, B1, C0, C1);
    ITER(k0 + 8,  B0, B1, C0, C1, A0, A1);
    ITER(k0 + 16, C0, C1, A0, A1, B0, B1);
  }

  const int fglob = fg * 4 + tf;
  const size_t obase = ((size_t)b * NFILT + fglob) * T_OUT;
  const int tg = base + t0;
  if (tg + 16 <= T_OUT) {
    #pragma unroll
    for (int c = 0; c < 8; ++c) {
      *(float2*)&outp[obase + tg + 2 * c] = make_float2(acc[2 * c], acc[2 * c + 1]);
    }
  } else {
    #pragma unroll
    for (int r = 0; r < 16; ++r)
      if (tg + r < T_OUT) outp[obase + tg + r] = acc[r];
  }
}

// ---------------------------------------------------------------------------
extern "C" void kernel_launch(void* const* d_in, const int* in_sizes, int n_in,
                              void* d_out, int out_size, void* d_ws, size_t ws_size,
                              hipStream_t stream) {
  const float* x    = (const float*)d_in[0];
  const float* nf1  = (const float*)d_in[1];
  const float* nf2  = (const float*)d_in[2];
  const float* nf3  = (const float*)d_in[3];
  const float* nf4  = (const float*)d_in[4];
  const float* amp1 = (const float*)d_in[5];
  const float* amp2 = (const float*)d_in[6];
  float* Wf  = (float*)d_ws;    // 80 * 264 * 4 B = 84.5 KB scratch
  float* out = (float*)d_out;

  build_filters_kernel<<<NFILT, 256, 0, stream>>>(nf1, nf2, nf3, nf4, amp1, amp2, Wf);

  dim3 grid((T_OUT + NTB - 1) / NTB, NFILT / 4, 8);   // 63 x 20 x 8
  conv_kernel<<<grid, 256, 0, stream>>>(x, Wf, out);
}

// Round 2
// 62.727 us; speedup vs baseline: 4.4330x; 4.4330x over previous
//
#include <hip/hip_runtime.h>

#define FDIM   251
#define NFILT  80
#define KPAD   256        // K padded to 8 chunks of 32 (zeros past 250)
#define T_IN   64000
#define T_OUT  63750      // 64000 - 251 + 1
#define NCHUNK 1024       // output positions per block (4 waves x 16 strips x 16)
#define XS1OFF 656        // xs1 base (dwords); 656 % 32 == 16 -> bank-staggered vs xs0
#define XSTOT  1300       // 656 + 644 dwords of LDS

typedef short bf16x8 __attribute__((ext_vector_type(8)));
typedef float f32x4  __attribute__((ext_vector_type(4)));

__device__ __forceinline__ unsigned short f2bf(float f) {
  unsigned int u = __float_as_uint(f);
  unsigned int r = (u + 0x7fffu + ((u >> 16) & 1u)) >> 16;   // RNE
  return (unsigned short)r;
}
__device__ __forceinline__ unsigned int packbf(float a, float b) {
  return (unsigned int)f2bf(a) | ((unsigned int)f2bf(b) << 16);
}

// ---------------------------------------------------------------------------
// Filter construction: one block per filter. (validated in round 1; output
// stage now emits bf16 W[80][256], zero-padded past k=250, window applied)
// ---------------------------------------------------------------------------
__device__ __forceinline__ void norm_pm1_shared(float* a, float* scratch, int tid) {
  float v  = (tid < FDIM) ? a[tid] : 0.f;
  float mn = (tid < FDIM) ? v : 1e30f;
  float mx = (tid < FDIM) ? v : -1e30f;
  #pragma unroll
  for (int o = 32; o > 0; o >>= 1) {
    mn = fminf(mn, __shfl_down(mn, o));
    mx = fmaxf(mx, __shfl_down(mx, o));
  }
  const int wid = tid >> 6;
  if ((tid & 63) == 0) { scratch[wid] = mn; scratch[4 + wid] = mx; }
  __syncthreads();
  if (tid == 0) {
    scratch[0] = fminf(fminf(scratch[0], scratch[1]), fminf(scratch[2], scratch[3]));
    scratch[4] = fmaxf(fmaxf(scratch[4], scratch[5]), fmaxf(scratch[6], scratch[7]));
  }
  __syncthreads();
  const float gmn = scratch[0], gmx = scratch[4];
  const float nv = 2.f * (v - gmn) / (gmx - gmn + 1e-6f) - 1.f;
  __syncthreads();
  float s = (tid < FDIM) ? nv : 0.f;
  #pragma unroll
  for (int o = 32; o > 0; o >>= 1) s += __shfl_down(s, o);
  if ((tid & 63) == 0) scratch[wid] = s;
  __syncthreads();
  if (tid == 0) scratch[0] = (scratch[0] + scratch[1] + scratch[2] + scratch[3]) / 251.f;
  __syncthreads();
  const float mean = scratch[0];
  if (tid < FDIM) a[tid] = nv - mean;
  __syncthreads();
}

__global__ __launch_bounds__(256) void build_filters_kernel(
    const float* __restrict__ nf1, const float* __restrict__ nf2,
    const float* __restrict__ nf3, const float* __restrict__ nf4,
    const float* __restrict__ amp1, const float* __restrict__ amp2,
    unsigned short* __restrict__ Wbf) {
  __shared__ float ir1[FDIM], ir2[FDIM], casc[FDIM];
  __shared__ float scratch[8];
  const int f = blockIdx.x, tid = threadIdx.x;
  const float FS  = 16000.f;
  const float MF  = 50.f / 16000.f;
  const float PIF = 3.14159265358979323846f;
  const float TPI = 6.28318530717958647692f;

  const float f1 = fminf(fmaxf(fabsf(nf1[f]) + MF, 0.f), 0.5f);
  const float f2 = fminf(fmaxf(f1 + fabsf(nf2[f] - f1) + MF, 0.f), 0.5f);
  const float f3 = fminf(fmaxf(fabsf(nf3[f]) + MF, 0.f), 0.5f);
  const float f4 = fminf(fmaxf(f3 + fabsf(nf4[f] - f3) + MF, 0.f), 0.5f);
  const float a1 = fabsf(amp1[f]);
  const float a2 = fabsf(amp2[f]);

  if (tid < FDIM) {
    const float t = (float)(tid + 1) / FS;
    {
      const float fcs = 0.5f * (f1 + f2) * FS, bws = (f2 - f1) * FS;
      const float pb = PIF * bws;
      ir1[tid] = a1 * expf(-2.f * pb * pb * (t * t)) * cosf(TPI * fcs * t);
    }
    {
      const float fcs = 0.5f * (f3 + f4) * FS, bws = (f4 - f3) * FS;
      const float pb = PIF * bws;
      ir2[tid] = a2 * expf(-2.f * pb * pb * (t * t)) * cosf(TPI * fcs * t);
    }
  }
  __syncthreads();
  norm_pm1_shared(ir1, scratch, tid);
  norm_pm1_shared(ir2, scratch, tid);

  if (tid < FDIM) {
    const int i = tid;
    const int plo = (i - 125 > 0) ? (i - 125) : 0;
    const int phi = (i + 125 < 250) ? (i + 125) : 250;
    float s = 0.f;
    for (int p = plo; p <= phi; ++p) s += ir1[p] * ir2[p + 125 - i];
    casc[i] = s;
  }
  __syncthreads();
  norm_pm1_shared(casc, scratch, tid);

  if (tid < KPAD) {
    float v = 0.f;
    if (tid < FDIM) {
      const float win = 0.54f - 0.46f * cosf(TPI * ((float)tid / 250.f));
      v = casc[tid] * win;
    }
    Wbf[(size_t)f * KPAD + tid] = f2bf(v);
  }
}

// ---------------------------------------------------------------------------
// Implicit-GEMM conv via bf16 MFMA 16x16x32.
//   D[m=filter][n=time] = sum_k W[m][k] * x[n + k]
// Block: 4 waves, 1024 output positions (wave w -> strips s = i*4+w, i<16).
// x staged in LDS as TWO parity-shifted bf16-pair copies so every lane's
// 8-consecutive-bf16 B-fragment is 4 aligned dword reads:
//   xs0[i] = (x[2i], x[2i+1]),  xs1[i] = (x[2i+1], x[2i+2])
// W held in registers: 5 Mtiles x 8 kchunks = 40 frags (160 VGPR), loaded
// once per block from global bf16 W (L2-resident, 40 KB).
// ---------------------------------------------------------------------------
__global__ __launch_bounds__(256, 2) void conv_mfma_kernel(
    const float* __restrict__ xin, const unsigned short* __restrict__ Wbf,
    float* __restrict__ outp) {
  __shared__ unsigned int xs[XSTOT];
  const int tid = threadIdx.x;
  const int n0  = blockIdx.x * NCHUNK;
  const int b   = blockIdx.y;
  const int l   = tid & 63, w = tid >> 6;
  const int m   = l & 15, h = l >> 4;

  // ---- W fragments: A[m=l&15][k = 8*h + j + 32*c] ----
  const short* Wp = (const short*)Wbf;
  bf16x8 afr[5][8];
  #pragma unroll
  for (int mt = 0; mt < 5; ++mt)
    #pragma unroll
    for (int c = 0; c < 8; ++c)
      afr[mt][c] = *(const bf16x8*)(Wp + (mt * 16 + m) * KPAD + c * 32 + h * 8);

  // ---- stage x window [n0, n0 + 1287] as parity pair copies ----
  const float* xg = xin + (size_t)b * T_IN;
  for (int i = tid; i < 644; i += 256) {
    const int g = n0 + 2 * i;
    const float a0 = (g     < T_IN) ? xg[g]     : 0.f;
    const float a1 = (g + 1 < T_IN) ? xg[g + 1] : 0.f;
    const float a2 = (g + 2 < T_IN) ? xg[g + 2] : 0.f;
    xs[i]          = packbf(a0, a1);
    xs[XS1OFF + i] = packbf(a1, a2);
  }
  __syncthreads();

  // lane-constant B addressing: S = t_loc + 32c + m + 8h, parity = m&1
  const unsigned int* psrc = xs + ((m & 1) ? XS1OFF : 0);
  const int lane_off = (8 * h + (m & ~1)) >> 1;   // (S - 32c - t_loc)>>1

  for (int i = 0; i < 16; ++i) {
    const int t_loc = i * 64 + w * 16;
    const int bbase = (t_loc >> 1) + lane_off;

    f32x4 acc[5];
    #pragma unroll
    for (int mt = 0; mt < 5; ++mt) acc[mt] = (f32x4){0.f, 0.f, 0.f, 0.f};

    #pragma unroll
    for (int c = 0; c < 8; ++c) {
      union { unsigned int u[4]; bf16x8 v; } bf;
      bf.u[0] = psrc[bbase + 16 * c + 0];
      bf.u[1] = psrc[bbase + 16 * c + 1];
      bf.u[2] = psrc[bbase + 16 * c + 2];
      bf.u[3] = psrc[bbase + 16 * c + 3];
      #pragma unroll
      for (int mt = 0; mt < 5; ++mt)
        acc[mt] = __builtin_amdgcn_mfma_f32_16x16x32_bf16(afr[mt][c], bf.v, acc[mt], 0, 0, 0);
    }

    const int tglob = n0 + t_loc + m;     // D col = l&15
    if (tglob < T_OUT) {
      #pragma unroll
      for (int mt = 0; mt < 5; ++mt)
        #pragma unroll
        for (int r = 0; r < 4; ++r) {     // D row = 4*h + r
          const int f = mt * 16 + 4 * h + r;
          outp[((size_t)b * NFILT + f) * T_OUT + tglob] = acc[mt][r];
        }
    }
  }
}

// ---------------------------------------------------------------------------
extern "C" void kernel_launch(void* const* d_in, const int* in_sizes, int n_in,
                              void* d_out, int out_size, void* d_ws, size_t ws_size,
                              hipStream_t stream) {
  const float* x    = (const float*)d_in[0];
  const float* nf1  = (const float*)d_in[1];
  const float* nf2  = (const float*)d_in[2];
  const float* nf3  = (const float*)d_in[3];
  const float* nf4  = (const float*)d_in[4];
  const float* amp1 = (const float*)d_in[5];
  const float* amp2 = (const float*)d_in[6];
  unsigned short* Wbf = (unsigned short*)d_ws;   // 80*256*2 = 40 KB scratch
  float* out = (float*)d_out;

  build_filters_kernel<<<NFILT, 256, 0, stream>>>(nf1, nf2, nf3, nf4, amp1, amp2, Wbf);

  dim3 grid((T_OUT + NCHUNK - 1) / NCHUNK, 8, 1);   // 63 x 8
  conv_mfma_kernel<<<grid, 256, 0, stream>>>(x, Wbf, out);
}